// Round 7
// baseline (479.529 us; speedup 1.0000x reference)
//
#include <hip/hip_runtime.h>
#include <hip/hip_cooperative_groups.h>

namespace cg = cooperative_groups;

#define BATCH   32768
#define NBLOCKS 256
#define NTHREADS 512
#define NWAVES  8

// LDS byte layout:
//   [0, 16384)        W1^T frags  (8 Mtiles x 2 Ktiles x 1KB)
//   [16384, 49152)    W2^T frags  (8 x 4 x 1KB)  -- m=0..5 also homed in AGPRs
//   [49152, 65536)    W3^T frags  (4 x 4 x 1KB)
//   [65536, 131072)   8 waves x 8KB scratch
//   [131072, 132352)  bias f32: b1[128] b2[128] b3[64]
#define LDS_BYTES 132352

typedef short    bf16x8 __attribute__((ext_vector_type(8)));
typedef float    f32x4  __attribute__((ext_vector_type(4)));
typedef unsigned u32x2  __attribute__((ext_vector_type(2)));
typedef float    f4v    __attribute__((ext_vector_type(4)));

#define A21 ((float)(1.0/5.0))
#define A31 ((float)(3.0/40.0))
#define A32 ((float)(9.0/40.0))
#define A41 ((float)(44.0/45.0))
#define A42 ((float)(-56.0/15.0))
#define A43 ((float)(32.0/9.0))
#define A51 ((float)(19372.0/6561.0))
#define A52 ((float)(-25360.0/2187.0))
#define A53 ((float)(64448.0/6561.0))
#define A54 ((float)(-212.0/729.0))
#define A61 ((float)(9017.0/3168.0))
#define A62 ((float)(-355.0/33.0))
#define A63 ((float)(46732.0/5247.0))
#define A64 ((float)(49.0/176.0))
#define A65 ((float)(-5103.0/18656.0))
#define BB1 ((float)(35.0/384.0))
#define BB3 ((float)(500.0/1113.0))
#define BB4 ((float)(125.0/192.0))
#define BB5 ((float)(-2187.0/6784.0))
#define BB6 ((float)(11.0/84.0))
#define E1 (BB1 - (float)(5179.0/57600.0))
#define E3 (BB3 - (float)(7571.0/16695.0))
#define E4 (BB4 - (float)(393.0/640.0))
#define E5 (BB5 - (float)(-92097.0/339200.0))
#define E6 (BB6 - (float)(187.0/2100.0))
#define E7 (0.0f - (float)(1.0/40.0))

#define RTOL_C 1e-3f
#define ATOL_C 1e-3f
#define SAFETY_C 0.9f
#define MINFAC_C 0.2f
#define MAXFAC_C 10.0f
#define H0_C 0.05f
#define T_DONE ((float)(1.0 - 1e-7))

// bf16 round-to-nearest-even helpers (bit pattern in low 16)
__device__ __forceinline__ unsigned bfr(float x) {
    unsigned u = __builtin_bit_cast(unsigned, x);
    return (u + 0x7fffu + ((u >> 16) & 1u)) >> 16;
}
__device__ __forceinline__ unsigned pack2bf(float a, float b) {
    return bfr(a) | (bfr(b) << 16);
}
__device__ __forceinline__ float bfhi(float a) {
    return __builtin_bit_cast(float, bfr(a) << 16);
}

// 24 W2 A-fragments (m=0..5, kt=0..3), named members only (no arrays -> no
// SROA/scratch risk). Homed in AGPRs via "+a" launder after load; MFMA
// builtins read A-operands from AGPRs natively on gfx950.
struct W2Frags {
    bf16x8 a00, a01, a02, a03;
    bf16x8 a10, a11, a12, a13;
    bf16x8 a20, a21, a22, a23;
    bf16x8 a30, a31, a32, a33;
    bf16x8 a40, a41, a42, a43;
    bf16x8 a50, a51, a52, a53;
};

// f(y) for the wave's 16 batch rows, fully MFMA.
// State layout: lane (b = lane&15, g = lane>>4) owns batch row b, dims m*16+4g+r.
// W2 A-frags m=0..5 come from AGPR-homed registers; m=6,7 and W1/W3 from LDS.
// scr: per-wave 8KB; lifetimes: ybuf[0,4K) -> h1_lo[0,4K)+h1_hi[4K,8K) -> h2[0,4K).
__device__ __forceinline__ void feval16(
    const char* __restrict__ wf, const float* __restrict__ biasf,
    const W2Frags& w2,
    char* scr, const int lane, const int b, const int g, const int swzx,
    const float (&ys)[16], float (&kout)[16])
{
    // ---- stage ys -> ybuf (hi/lo planes, [16][64] bf16, swizzled) ----
#pragma unroll
    for (int m = 0; m < 4; ++m) {
        const float a0 = ys[4*m], a1 = ys[4*m+1], a2 = ys[4*m+2], a3 = ys[4*m+3];
        u32x2 vh, vl;
        vh.x = pack2bf(a0, a1); vh.y = pack2bf(a2, a3);
        vl.x = pack2bf(a0 - bfhi(a0), a1 - bfhi(a1));
        vl.y = pack2bf(a2 - bfhi(a2), a3 - bfhi(a3));
        const int off = (b*128 + (m*16 + 4*g)*2) ^ swzx;
        *(u32x2*)(scr + off)        = vh;
        *(u32x2*)(scr + 2048 + off) = vl;
    }
    __builtin_amdgcn_wave_barrier();
    // ---- L1: B-frags from ybuf ----
    bf16x8 Bh0, Bh1, Bl0, Bl1;
    {
        const int o0 = (b*128 + 16*g) ^ swzx;
        const int o1 = (b*128 + 64 + 16*g) ^ swzx;
        Bh0 = *(const bf16x8*)(scr + o0);
        Bh1 = *(const bf16x8*)(scr + o1);
        Bl0 = *(const bf16x8*)(scr + 2048 + o0);
        Bl1 = *(const bf16x8*)(scr + 2048 + o1);
    }
    __builtin_amdgcn_wave_barrier();
#pragma unroll
    for (int m = 0; m < 8; ++m) {
        f32x4 acc = {0.f, 0.f, 0.f, 0.f};
        const bf16x8 A0 = *(const bf16x8*)(wf + (m*2+0)*1024 + lane*16);
        const bf16x8 A1 = *(const bf16x8*)(wf + (m*2+1)*1024 + lane*16);
        acc = __builtin_amdgcn_mfma_f32_16x16x32_bf16(A0, Bh0, acc, 0, 0, 0);
        acc = __builtin_amdgcn_mfma_f32_16x16x32_bf16(A1, Bh1, acc, 0, 0, 0);
        acc = __builtin_amdgcn_mfma_f32_16x16x32_bf16(A0, Bl0, acc, 0, 0, 0);
        acc = __builtin_amdgcn_mfma_f32_16x16x32_bf16(A1, Bl1, acc, 0, 0, 0);
        const f4v bia = *(const f4v*)(biasf + m*16 + 4*g);
        const float v0 = fmaxf(acc[0] + bia.x, 0.f);
        const float v1 = fmaxf(acc[1] + bia.y, 0.f);
        const float v2 = fmaxf(acc[2] + bia.z, 0.f);
        const float v3 = fmaxf(acc[3] + bia.w, 0.f);
        u32x2 vh, vl;
        vh.x = pack2bf(v0, v1); vh.y = pack2bf(v2, v3);
        vl.x = pack2bf(v0 - bfhi(v0), v1 - bfhi(v1));
        vl.y = pack2bf(v2 - bfhi(v2), v3 - bfhi(v3));
        const int off = (b*256 + (m*16 + 4*g)*2) ^ swzx;
        *(u32x2*)(scr + 4096 + off) = vh;     // h1_hi
        *(u32x2*)(scr + off)        = vl;     // h1_lo (ybuf dead)
    }
    __builtin_amdgcn_wave_barrier();
    // ---- L2 (A-frags m<6 from AGPRs, m=6,7 from LDS) ----
    bf16x8 B2h[4], B2l[4];
#pragma unroll
    for (int kt = 0; kt < 4; ++kt) {
        const int off = (b*256 + 64*kt + 16*g) ^ swzx;
        B2h[kt] = *(const bf16x8*)(scr + 4096 + off);
        B2l[kt] = *(const bf16x8*)(scr + off);
    }
    __builtin_amdgcn_wave_barrier();

#define L2_TILE(mm, AK0, AK1, AK2, AK3) do {                                   \
    f32x4 acc = {0.f, 0.f, 0.f, 0.f};                                          \
    acc = __builtin_amdgcn_mfma_f32_16x16x32_bf16(AK0, B2h[0], acc, 0, 0, 0);  \
    acc = __builtin_amdgcn_mfma_f32_16x16x32_bf16(AK0, B2l[0], acc, 0, 0, 0);  \
    acc = __builtin_amdgcn_mfma_f32_16x16x32_bf16(AK1, B2h[1], acc, 0, 0, 0);  \
    acc = __builtin_amdgcn_mfma_f32_16x16x32_bf16(AK1, B2l[1], acc, 0, 0, 0);  \
    acc = __builtin_amdgcn_mfma_f32_16x16x32_bf16(AK2, B2h[2], acc, 0, 0, 0);  \
    acc = __builtin_amdgcn_mfma_f32_16x16x32_bf16(AK2, B2l[2], acc, 0, 0, 0);  \
    acc = __builtin_amdgcn_mfma_f32_16x16x32_bf16(AK3, B2h[3], acc, 0, 0, 0);  \
    acc = __builtin_amdgcn_mfma_f32_16x16x32_bf16(AK3, B2l[3], acc, 0, 0, 0);  \
    const f4v bia = *(const f4v*)(biasf + 128 + (mm)*16 + 4*g);                \
    const float v0 = fmaxf(acc[0] + bia.x, 0.f);                               \
    const float v1 = fmaxf(acc[1] + bia.y, 0.f);                               \
    const float v2 = fmaxf(acc[2] + bia.z, 0.f);                               \
    const float v3 = fmaxf(acc[3] + bia.w, 0.f);                               \
    u32x2 vh; vh.x = pack2bf(v0, v1); vh.y = pack2bf(v2, v3);                  \
    *(u32x2*)(scr + ((b*256 + ((mm)*16 + 4*g)*2) ^ swzx)) = vh;                \
} while (0)

    L2_TILE(0, w2.a00, w2.a01, w2.a02, w2.a03);
    L2_TILE(1, w2.a10, w2.a11, w2.a12, w2.a13);
    L2_TILE(2, w2.a20, w2.a21, w2.a22, w2.a23);
    L2_TILE(3, w2.a30, w2.a31, w2.a32, w2.a33);
    L2_TILE(4, w2.a40, w2.a41, w2.a42, w2.a43);
    L2_TILE(5, w2.a50, w2.a51, w2.a52, w2.a53);
    {
        const bf16x8 A0 = *(const bf16x8*)(wf + 16384 + (6*4+0)*1024 + lane*16);
        const bf16x8 A1 = *(const bf16x8*)(wf + 16384 + (6*4+1)*1024 + lane*16);
        const bf16x8 A2 = *(const bf16x8*)(wf + 16384 + (6*4+2)*1024 + lane*16);
        const bf16x8 A3 = *(const bf16x8*)(wf + 16384 + (6*4+3)*1024 + lane*16);
        L2_TILE(6, A0, A1, A2, A3);
    }
    {
        const bf16x8 A0 = *(const bf16x8*)(wf + 16384 + (7*4+0)*1024 + lane*16);
        const bf16x8 A1 = *(const bf16x8*)(wf + 16384 + (7*4+1)*1024 + lane*16);
        const bf16x8 A2 = *(const bf16x8*)(wf + 16384 + (7*4+2)*1024 + lane*16);
        const bf16x8 A3 = *(const bf16x8*)(wf + 16384 + (7*4+3)*1024 + lane*16);
        L2_TILE(7, A0, A1, A2, A3);
    }
#undef L2_TILE

    __builtin_amdgcn_wave_barrier();
    // ---- L3 ----
    bf16x8 B3[4];
#pragma unroll
    for (int kt = 0; kt < 4; ++kt)
        B3[kt] = *(const bf16x8*)(scr + ((b*256 + 64*kt + 16*g) ^ swzx));
    __builtin_amdgcn_wave_barrier();
#pragma unroll
    for (int m = 0; m < 4; ++m) {
        f32x4 acc = {0.f, 0.f, 0.f, 0.f};
#pragma unroll
        for (int kt = 0; kt < 4; ++kt) {
            const bf16x8 A = *(const bf16x8*)(wf + 49152 + (m*4+kt)*1024 + lane*16);
            acc = __builtin_amdgcn_mfma_f32_16x16x32_bf16(A, B3[kt], acc, 0, 0, 0);
        }
        const f4v bia = *(const f4v*)(biasf + 256 + m*16 + 4*g);
        kout[4*m+0] = acc[0] + bia.x;
        kout[4*m+1] = acc[1] + bia.y;
        kout[4*m+2] = acc[2] + bia.z;
        kout[4*m+3] = acc[3] + bia.w;
    }
}

__global__ __launch_bounds__(NTHREADS)
__attribute__((amdgpu_waves_per_eu(2, 2)))
void ode_kernel(
    const float* __restrict__ x,
    const float* __restrict__ gW1, const float* __restrict__ gb1,
    const float* __restrict__ gW2, const float* __restrict__ gb2,
    const float* __restrict__ gW3, const float* __restrict__ gb3,
    float* __restrict__ Y, float* __restrict__ ws)
{
    extern __shared__ float lds[];
    char*  ldsb  = (char*)lds;
    short* wfrag = (short*)ldsb;
    float* biasf = (float*)(ldsb + 131072);

    const int tid  = threadIdx.x;
    const int lane = tid & 63;
    const int wid  = tid >> 6;
    const int bid  = blockIdx.x;
    const int b    = lane & 15;
    const int g    = lane >> 4;
    const int swzx = (b & 7) << 4;

    // ---- stage weights as frag-linear bf16 tiles (once) ----
    for (int i = tid; i < 8192; i += NTHREADS) {       // W1: 16 tiles (m*2+kt)
        const int t = i >> 9, l = (i >> 3) & 63, j = i & 7;
        const int m = t >> 1, kt = t & 1;
        const int row = kt*32 + (l>>4)*8 + j, col = m*16 + (l&15);
        wfrag[i] = (short)bfr(gW1[row*128 + col]);
    }
    for (int i = tid; i < 16384; i += NTHREADS) {      // W2: 32 tiles (m*4+kt)
        const int t = i >> 9, l = (i >> 3) & 63, j = i & 7;
        const int m = t >> 2, kt = t & 3;
        const int row = kt*32 + (l>>4)*8 + j, col = m*16 + (l&15);
        wfrag[8192 + i] = (short)bfr(gW2[row*128 + col]);
    }
    for (int i = tid; i < 8192; i += NTHREADS) {       // W3: 16 tiles (m*4+kt)
        const int t = i >> 9, l = (i >> 3) & 63, j = i & 7;
        const int m = t >> 2, kt = t & 3;
        const int row = kt*32 + (l>>4)*8 + j, col = m*16 + (l&15);
        wfrag[24576 + i] = (short)bfr(gW3[row*64 + col]);
    }
    for (int i = tid; i < 128; i += NTHREADS) biasf[i]       = gb1[i];
    for (int i = tid; i < 128; i += NTHREADS) biasf[128 + i] = gb2[i];
    for (int i = tid; i < 64;  i += NTHREADS) biasf[256 + i] = gb3[i];
    __syncthreads();

    // ---- hoist W2 A-frags m=0..5 and pin them in AGPRs (one-time) ----
    W2Frags w2;
#define LW2(mm, f0, f1, f2, f3)                                                 \
    w2.f0 = *(const bf16x8*)(ldsb + 16384 + ((mm)*4+0)*1024 + lane*16);         \
    w2.f1 = *(const bf16x8*)(ldsb + 16384 + ((mm)*4+1)*1024 + lane*16);         \
    w2.f2 = *(const bf16x8*)(ldsb + 16384 + ((mm)*4+2)*1024 + lane*16);         \
    w2.f3 = *(const bf16x8*)(ldsb + 16384 + ((mm)*4+3)*1024 + lane*16);         \
    asm("" : "+a"(w2.f0), "+a"(w2.f1), "+a"(w2.f2), "+a"(w2.f3));
    LW2(0, a00, a01, a02, a03)
    LW2(1, a10, a11, a12, a13)
    LW2(2, a20, a21, a22, a23)
    LW2(3, a30, a31, a32, a33)
    LW2(4, a40, a41, a42, a43)
    LW2(5, a50, a51, a52, a53)
#undef LW2

    char* scr = ldsb + 65536 + wid * 8192;
    float* wavepart = ws;                     // [2][2048] ping-pong

    cg::grid_group grid = cg::this_grid();
    const int row0 = bid * 128 + wid * 16;

    // persistent state: lane owns batch row0+b, dims m*16+4g+r  (idx = m*4+r)
    float y[16], k1[16];

    // ---- prepass: y = x; k1 = f(y) ----
    {
        float ysv[16];
#pragma unroll
        for (int m = 0; m < 4; ++m) {
            const f4v v = *(const f4v*)(x + (row0 + b) * 64 + m*16 + 4*g);
            ysv[4*m+0] = v.x; ysv[4*m+1] = v.y; ysv[4*m+2] = v.z; ysv[4*m+3] = v.w;
        }
#pragma unroll
        for (int i = 0; i < 16; ++i) y[i] = ysv[i];
        feval16(ldsb, biasf, w2, scr, lane, b, g, swzx, ysv, k1);
    }

    float t = 0.0f, h = H0_C;
    bool done = false;

#pragma unroll 1
    for (int iter = 0; iter < 64; ++iter) {
        const float hs = fminf(h, 1.0f - t);
        float sq = 0.0f;
        float y5[16], k7[16];

        // ---- straight-line dopri5 stages (precise liveness) ----
        {
            float ysv[16];
            float k2[16], k3[16], k4[16], k5[16], k6[16], errp[16];

#pragma unroll
            for (int i = 0; i < 16; ++i) ysv[i] = y[i] + hs * (A21 * k1[i]);
            feval16(ldsb, biasf, w2, scr, lane, b, g, swzx, ysv, k2);

#pragma unroll
            for (int i = 0; i < 16; ++i) ysv[i] = y[i] + hs * (A31 * k1[i] + A32 * k2[i]);
            feval16(ldsb, biasf, w2, scr, lane, b, g, swzx, ysv, k3);

#pragma unroll
            for (int i = 0; i < 16; ++i) ysv[i] = y[i] + hs * (A41 * k1[i] + A42 * k2[i] + A43 * k3[i]);
            feval16(ldsb, biasf, w2, scr, lane, b, g, swzx, ysv, k4);

#pragma unroll
            for (int i = 0; i < 16; ++i) ysv[i] = y[i] + hs * (A51 * k1[i] + A52 * k2[i] + A53 * k3[i] + A54 * k4[i]);
            feval16(ldsb, biasf, w2, scr, lane, b, g, swzx, ysv, k5);

#pragma unroll
            for (int i = 0; i < 16; ++i) ysv[i] = y[i] + hs * (A61 * k1[i] + A62 * k2[i] + A63 * k3[i] + A64 * k4[i] + A65 * k5[i]);
            feval16(ldsb, biasf, w2, scr, lane, b, g, swzx, ysv, k6);   // k2 dead

#pragma unroll
            for (int i = 0; i < 16; ++i) {
                ysv[i]  = y[i] + hs * (BB1 * k1[i] + BB3 * k3[i] + BB4 * k4[i] + BB5 * k5[i] + BB6 * k6[i]);
                y5[i]   = ysv[i];
                errp[i] = hs * (E1 * k1[i] + E3 * k3[i] + E4 * k4[i] + E5 * k5[i] + E6 * k6[i]);
            }                                                            // k3..k6 dead
            feval16(ldsb, biasf, w2, scr, lane, b, g, swzx, ysv, k7);

#pragma unroll
            for (int i = 0; i < 16; ++i) {
                const float er = errp[i] + hs * (E7 * k7[i]);
                const float sc = ATOL_C + RTOL_C * fmaxf(fabsf(y[i]), fabsf(y5[i]));
                const float q = er / sc;
                sq += q * q;
            }
        }

        // wave butterfly reduce (bitwise identical on all lanes)
#pragma unroll
        for (int off = 32; off > 0; off >>= 1) sq += __shfl_xor(sq, off);
        if (lane == 0)
            __hip_atomic_store(&wavepart[(iter & 1) * 2048 + bid * 8 + wid], sq,
                               __ATOMIC_RELEASE, __HIP_MEMORY_SCOPE_AGENT);
        grid.sync();

        // every wave redundantly sums all 2048 partials in identical fixed order
        float psum = 0.0f;
        const float* wp = wavepart + (iter & 1) * 2048;
#pragma unroll 4
        for (int k = 0; k < 32; ++k)
            psum += __hip_atomic_load(&wp[lane + 64 * k], __ATOMIC_RELAXED, __HIP_MEMORY_SCOPE_AGENT);
#pragma unroll
        for (int off = 32; off > 0; off >>= 1) psum += __shfl_xor(psum, off);
        const float tot = psum;

        const float err_norm = sqrtf(tot * (1.0f / (float)(BATCH * 64)));
        const bool accept = (err_norm <= 1.0f) && (!done);
        float factor = SAFETY_C * powf(fmaxf(err_norm, 1e-10f), -0.2f);
        factor = fminf(fmaxf(factor, MINFAC_C), MAXFAC_C);

        if (accept) {
#pragma unroll
            for (int i = 0; i < 16; ++i) { y[i] = y5[i]; k1[i] = k7[i]; }
            t = t + hs;
        }
        h = hs * factor;
        done = done || (t >= T_DONE);
        if (done) break;   // uniform: identical err_norm in every block
    }

    // final store
#pragma unroll
    for (int m = 0; m < 4; ++m) {
        f4v v;
        v.x = y[4*m+0]; v.y = y[4*m+1]; v.z = y[4*m+2]; v.w = y[4*m+3];
        *(f4v*)(Y + (row0 + b) * 64 + m*16 + 4*g) = v;
    }
}

extern "C" void kernel_launch(void* const* d_in, const int* in_sizes, int n_in,
                              void* d_out, int out_size, void* d_ws, size_t ws_size,
                              hipStream_t stream) {
    const float* x  = (const float*)d_in[0];
    const float* W1 = (const float*)d_in[1];
    const float* b1 = (const float*)d_in[2];
    const float* W2 = (const float*)d_in[3];
    const float* b2 = (const float*)d_in[4];
    const float* W3 = (const float*)d_in[5];
    const float* b3 = (const float*)d_in[6];
    float* Y  = (float*)d_out;
    float* ws = (float*)d_ws;

    const size_t need = (size_t)(2 * 2048) * sizeof(float);
    if (ws_size < need) return;

    (void)hipFuncSetAttribute(reinterpret_cast<const void*>(ode_kernel),
                              hipFuncAttributeMaxDynamicSharedMemorySize, LDS_BYTES);

    void* args[] = {(void*)&x, (void*)&W1, (void*)&b1, (void*)&W2, (void*)&b2,
                    (void*)&W3, (void*)&b3, (void*)&Y, (void*)&ws};
    (void)hipLaunchCooperativeKernel(reinterpret_cast<const void*>(ode_kernel),
                                     dim3(NBLOCKS), dim3(NTHREADS),
                                     args, LDS_BYTES, stream);
}

// Round 8
// 453.608 us; speedup vs baseline: 1.0571x; 1.0571x over previous
//
#include <hip/hip_runtime.h>
#include <hip/hip_cooperative_groups.h>

namespace cg = cooperative_groups;

#define BATCH   32768
#define NBLOCKS 256
#define NTHREADS 512
#define NWAVES  8

// LDS byte layout:
//   [0, 16384)        W1^T frags  (8 Mtiles x 2 Ktiles x 1KB)
//   [16384, 49152)    (unused; W2 frags live in d_ws and are read via L1/L2)
//   [49152, 65536)    W3^T frags  (4 x 4 x 1KB)
//   [65536, 131072)   8 waves x 8KB scratch
//   [131072, 132352)  bias f32: b1[128] b2[128] b3[64]
#define LDS_BYTES 132352

typedef short    bf16x8 __attribute__((ext_vector_type(8)));
typedef float    f32x4  __attribute__((ext_vector_type(4)));
typedef unsigned u32x2  __attribute__((ext_vector_type(2)));
typedef float    f4v    __attribute__((ext_vector_type(4)));

#define A21 ((float)(1.0/5.0))
#define A31 ((float)(3.0/40.0))
#define A32 ((float)(9.0/40.0))
#define A41 ((float)(44.0/45.0))
#define A42 ((float)(-56.0/15.0))
#define A43 ((float)(32.0/9.0))
#define A51 ((float)(19372.0/6561.0))
#define A52 ((float)(-25360.0/2187.0))
#define A53 ((float)(64448.0/6561.0))
#define A54 ((float)(-212.0/729.0))
#define A61 ((float)(9017.0/3168.0))
#define A62 ((float)(-355.0/33.0))
#define A63 ((float)(46732.0/5247.0))
#define A64 ((float)(49.0/176.0))
#define A65 ((float)(-5103.0/18656.0))
#define BB1 ((float)(35.0/384.0))
#define BB3 ((float)(500.0/1113.0))
#define BB4 ((float)(125.0/192.0))
#define BB5 ((float)(-2187.0/6784.0))
#define BB6 ((float)(11.0/84.0))
#define E1 (BB1 - (float)(5179.0/57600.0))
#define E3 (BB3 - (float)(7571.0/16695.0))
#define E4 (BB4 - (float)(393.0/640.0))
#define E5 (BB5 - (float)(-92097.0/339200.0))
#define E6 (BB6 - (float)(187.0/2100.0))
#define E7 (0.0f - (float)(1.0/40.0))

#define RTOL_C 1e-3f
#define ATOL_C 1e-3f
#define SAFETY_C 0.9f
#define MINFAC_C 0.2f
#define MAXFAC_C 10.0f
#define H0_C 0.05f
#define T_DONE ((float)(1.0 - 1e-7))

// bf16 round-to-nearest-even helpers (bit pattern in low 16)
__device__ __forceinline__ unsigned bfr(float x) {
    unsigned u = __builtin_bit_cast(unsigned, x);
    return (u + 0x7fffu + ((u >> 16) & 1u)) >> 16;
}
__device__ __forceinline__ unsigned pack2bf(float a, float b) {
    return bfr(a) | (bfr(b) << 16);
}
__device__ __forceinline__ float bfhi(float a) {
    return __builtin_bit_cast(float, bfr(a) << 16);
}

// f(y) for the wave's 16 batch rows, fully MFMA.
// State layout: lane (b = lane&15, g = lane>>4) owns batch row b, dims m*16+4g+r.
// W1/W3 A-frags from LDS; W2 A-frags from global (L1-resident, off the LDS pipe).
// scr: per-wave 8KB; lifetimes: ybuf[0,4K) -> h1_lo[0,4K)+h1_hi[4K,8K) -> h2[0,4K).
__device__ __forceinline__ void feval16(
    const char* __restrict__ wf, const char* __restrict__ w2g,
    const float* __restrict__ biasf,
    char* scr, const int lane, const int b, const int g, const int swzx,
    const float (&ys)[16], float (&kout)[16])
{
    // ---- stage ys -> ybuf (hi/lo planes, [16][64] bf16, swizzled) ----
#pragma unroll
    for (int m = 0; m < 4; ++m) {
        const float a0 = ys[4*m], a1 = ys[4*m+1], a2 = ys[4*m+2], a3 = ys[4*m+3];
        u32x2 vh, vl;
        vh.x = pack2bf(a0, a1); vh.y = pack2bf(a2, a3);
        vl.x = pack2bf(a0 - bfhi(a0), a1 - bfhi(a1));
        vl.y = pack2bf(a2 - bfhi(a2), a3 - bfhi(a3));
        const int off = (b*128 + (m*16 + 4*g)*2) ^ swzx;
        *(u32x2*)(scr + off)        = vh;
        *(u32x2*)(scr + 2048 + off) = vl;
    }
    __builtin_amdgcn_wave_barrier();
    // ---- L1: B-frags from ybuf ----
    bf16x8 Bh0, Bh1, Bl0, Bl1;
    {
        const int o0 = (b*128 + 16*g) ^ swzx;
        const int o1 = (b*128 + 64 + 16*g) ^ swzx;
        Bh0 = *(const bf16x8*)(scr + o0);
        Bh1 = *(const bf16x8*)(scr + o1);
        Bl0 = *(const bf16x8*)(scr + 2048 + o0);
        Bl1 = *(const bf16x8*)(scr + 2048 + o1);
    }
    __builtin_amdgcn_wave_barrier();
#pragma unroll
    for (int m = 0; m < 8; ++m) {
        f32x4 acc = {0.f, 0.f, 0.f, 0.f};
        const bf16x8 A0 = *(const bf16x8*)(wf + (m*2+0)*1024 + lane*16);
        const bf16x8 A1 = *(const bf16x8*)(wf + (m*2+1)*1024 + lane*16);
        acc = __builtin_amdgcn_mfma_f32_16x16x32_bf16(A0, Bh0, acc, 0, 0, 0);
        acc = __builtin_amdgcn_mfma_f32_16x16x32_bf16(A1, Bh1, acc, 0, 0, 0);
        acc = __builtin_amdgcn_mfma_f32_16x16x32_bf16(A0, Bl0, acc, 0, 0, 0);
        acc = __builtin_amdgcn_mfma_f32_16x16x32_bf16(A1, Bl1, acc, 0, 0, 0);
        const f4v bia = *(const f4v*)(biasf + m*16 + 4*g);
        const float v0 = fmaxf(acc[0] + bia.x, 0.f);
        const float v1 = fmaxf(acc[1] + bia.y, 0.f);
        const float v2 = fmaxf(acc[2] + bia.z, 0.f);
        const float v3 = fmaxf(acc[3] + bia.w, 0.f);
        u32x2 vh, vl;
        vh.x = pack2bf(v0, v1); vh.y = pack2bf(v2, v3);
        vl.x = pack2bf(v0 - bfhi(v0), v1 - bfhi(v1));
        vl.y = pack2bf(v2 - bfhi(v2), v3 - bfhi(v3));
        const int off = (b*256 + (m*16 + 4*g)*2) ^ swzx;
        *(u32x2*)(scr + 4096 + off) = vh;     // h1_hi
        *(u32x2*)(scr + off)        = vl;     // h1_lo (ybuf dead)
    }
    __builtin_amdgcn_wave_barrier();
    // ---- L2 (A-frags from GLOBAL via L1; B-frags from LDS) ----
    bf16x8 B2h[4], B2l[4];
#pragma unroll
    for (int kt = 0; kt < 4; ++kt) {
        const int off = (b*256 + 64*kt + 16*g) ^ swzx;
        B2h[kt] = *(const bf16x8*)(scr + 4096 + off);
        B2l[kt] = *(const bf16x8*)(scr + off);
    }
    __builtin_amdgcn_wave_barrier();
#pragma unroll
    for (int m = 0; m < 8; ++m) {
        f32x4 acc = {0.f, 0.f, 0.f, 0.f};
#pragma unroll
        for (int kt = 0; kt < 4; ++kt) {
            const bf16x8 A = *(const bf16x8*)(w2g + (m*4+kt)*1024 + lane*16);
            acc = __builtin_amdgcn_mfma_f32_16x16x32_bf16(A, B2h[kt], acc, 0, 0, 0);
            acc = __builtin_amdgcn_mfma_f32_16x16x32_bf16(A, B2l[kt], acc, 0, 0, 0);
        }
        const f4v bia = *(const f4v*)(biasf + 128 + m*16 + 4*g);
        const float v0 = fmaxf(acc[0] + bia.x, 0.f);
        const float v1 = fmaxf(acc[1] + bia.y, 0.f);
        const float v2 = fmaxf(acc[2] + bia.z, 0.f);
        const float v3 = fmaxf(acc[3] + bia.w, 0.f);
        u32x2 vh;
        vh.x = pack2bf(v0, v1); vh.y = pack2bf(v2, v3);
        const int off = (b*256 + (m*16 + 4*g)*2) ^ swzx;
        *(u32x2*)(scr + off) = vh;            // h2_hi (h1_lo dead)
    }
    __builtin_amdgcn_wave_barrier();
    // ---- L3 ----
    bf16x8 B3[4];
#pragma unroll
    for (int kt = 0; kt < 4; ++kt)
        B3[kt] = *(const bf16x8*)(scr + ((b*256 + 64*kt + 16*g) ^ swzx));
    __builtin_amdgcn_wave_barrier();
#pragma unroll
    for (int m = 0; m < 4; ++m) {
        f32x4 acc = {0.f, 0.f, 0.f, 0.f};
#pragma unroll
        for (int kt = 0; kt < 4; ++kt) {
            const bf16x8 A = *(const bf16x8*)(wf + 49152 + (m*4+kt)*1024 + lane*16);
            acc = __builtin_amdgcn_mfma_f32_16x16x32_bf16(A, B3[kt], acc, 0, 0, 0);
        }
        const f4v bia = *(const f4v*)(biasf + 256 + m*16 + 4*g);
        kout[4*m+0] = acc[0] + bia.x;
        kout[4*m+1] = acc[1] + bia.y;
        kout[4*m+2] = acc[2] + bia.z;
        kout[4*m+3] = acc[3] + bia.w;
    }
}

__global__ __launch_bounds__(NTHREADS)
__attribute__((amdgpu_waves_per_eu(2, 2)))
void ode_kernel(
    const float* __restrict__ x,
    const float* __restrict__ gW1, const float* __restrict__ gb1,
    const float* __restrict__ gW2, const float* __restrict__ gb2,
    const float* __restrict__ gW3, const float* __restrict__ gb3,
    float* __restrict__ Y, float* __restrict__ ws)
{
    extern __shared__ float lds[];
    char*  ldsb  = (char*)lds;
    short* wfrag = (short*)ldsb;
    float* biasf = (float*)(ldsb + 131072);

    const int tid  = threadIdx.x;
    const int lane = tid & 63;
    const int wid  = tid >> 6;
    const int bid  = blockIdx.x;
    const int b    = lane & 15;
    const int g    = lane >> 4;
    const int swzx = (b & 7) << 4;

    float* wavepart = ws;                       // [2][2048] ping-pong
    short* w2s = (short*)(ws + 4096);           // 16384 bf16 = 32 KB frag-linear W2

    // ---- stage W2 frags into d_ws (all blocks write identical bytes) ----
    for (int i = tid; i < 16384; i += NTHREADS) {      // W2: 32 tiles (m*4+kt)
        const int t = i >> 9, l = (i >> 3) & 63, j = i & 7;
        const int m = t >> 2, kt = t & 3;
        const int row = kt*32 + (l>>4)*8 + j, col = m*16 + (l&15);
        w2s[i] = (short)bfr(gW2[row*128 + col]);
    }
    // ---- stage W1/W3 frags + biases into LDS (once) ----
    for (int i = tid; i < 8192; i += NTHREADS) {       // W1: 16 tiles (m*2+kt)
        const int t = i >> 9, l = (i >> 3) & 63, j = i & 7;
        const int m = t >> 1, kt = t & 1;
        const int row = kt*32 + (l>>4)*8 + j, col = m*16 + (l&15);
        wfrag[i] = (short)bfr(gW1[row*128 + col]);
    }
    for (int i = tid; i < 8192; i += NTHREADS) {       // W3: 16 tiles (m*4+kt)
        const int t = i >> 9, l = (i >> 3) & 63, j = i & 7;
        const int m = t >> 2, kt = t & 3;
        const int row = kt*32 + (l>>4)*8 + j, col = m*16 + (l&15);
        wfrag[24576 + i] = (short)bfr(gW3[row*64 + col]);
    }
    for (int i = tid; i < 128; i += NTHREADS) biasf[i]       = gb1[i];
    for (int i = tid; i < 128; i += NTHREADS) biasf[128 + i] = gb2[i];
    for (int i = tid; i < 64;  i += NTHREADS) biasf[256 + i] = gb3[i];
    __syncthreads();   // drains vmcnt: own-block w2s writes visible to own reads

    const char* w2g = (const char*)w2s;
    char* scr = ldsb + 65536 + wid * 8192;

    cg::grid_group grid = cg::this_grid();
    const int row0 = bid * 128 + wid * 16;

    // persistent state: lane owns batch row0+b, dims m*16+4g+r  (idx = m*4+r)
    float y[16], k1[16];

    // ---- prepass: y = x; k1 = f(y) ----
    {
        float ysv[16];
#pragma unroll
        for (int m = 0; m < 4; ++m) {
            const f4v v = *(const f4v*)(x + (row0 + b) * 64 + m*16 + 4*g);
            ysv[4*m+0] = v.x; ysv[4*m+1] = v.y; ysv[4*m+2] = v.z; ysv[4*m+3] = v.w;
        }
#pragma unroll
        for (int i = 0; i < 16; ++i) y[i] = ysv[i];
        feval16(ldsb, w2g, biasf, scr, lane, b, g, swzx, ysv, k1);
    }

    float t = 0.0f, h = H0_C;
    bool done = false;

#pragma unroll 1
    for (int iter = 0; iter < 64; ++iter) {
        const float hs = fminf(h, 1.0f - t);
        float sq = 0.0f;
        float y5[16], k7[16];

        // ---- straight-line dopri5 stages (precise liveness) ----
        {
            float ysv[16];
            float k2[16], k3[16], k4[16], k5[16], k6[16], errp[16];

#pragma unroll
            for (int i = 0; i < 16; ++i) ysv[i] = y[i] + hs * (A21 * k1[i]);
            feval16(ldsb, w2g, biasf, scr, lane, b, g, swzx, ysv, k2);

#pragma unroll
            for (int i = 0; i < 16; ++i) ysv[i] = y[i] + hs * (A31 * k1[i] + A32 * k2[i]);
            feval16(ldsb, w2g, biasf, scr, lane, b, g, swzx, ysv, k3);

#pragma unroll
            for (int i = 0; i < 16; ++i) ysv[i] = y[i] + hs * (A41 * k1[i] + A42 * k2[i] + A43 * k3[i]);
            feval16(ldsb, w2g, biasf, scr, lane, b, g, swzx, ysv, k4);

#pragma unroll
            for (int i = 0; i < 16; ++i) ysv[i] = y[i] + hs * (A51 * k1[i] + A52 * k2[i] + A53 * k3[i] + A54 * k4[i]);
            feval16(ldsb, w2g, biasf, scr, lane, b, g, swzx, ysv, k5);

#pragma unroll
            for (int i = 0; i < 16; ++i) ysv[i] = y[i] + hs * (A61 * k1[i] + A62 * k2[i] + A63 * k3[i] + A64 * k4[i] + A65 * k5[i]);
            feval16(ldsb, w2g, biasf, scr, lane, b, g, swzx, ysv, k6);   // k2 dead

#pragma unroll
            for (int i = 0; i < 16; ++i) {
                ysv[i]  = y[i] + hs * (BB1 * k1[i] + BB3 * k3[i] + BB4 * k4[i] + BB5 * k5[i] + BB6 * k6[i]);
                y5[i]   = ysv[i];
                errp[i] = hs * (E1 * k1[i] + E3 * k3[i] + E4 * k4[i] + E5 * k5[i] + E6 * k6[i]);
            }                                                            // k3..k6 dead
            feval16(ldsb, w2g, biasf, scr, lane, b, g, swzx, ysv, k7);

#pragma unroll
            for (int i = 0; i < 16; ++i) {
                const float er = errp[i] + hs * (E7 * k7[i]);
                const float sc = ATOL_C + RTOL_C * fmaxf(fabsf(y[i]), fabsf(y5[i]));
                const float q = er / sc;
                sq += q * q;
            }
        }

        // wave butterfly reduce (bitwise identical on all lanes)
#pragma unroll
        for (int off = 32; off > 0; off >>= 1) sq += __shfl_xor(sq, off);
        if (lane == 0)
            __hip_atomic_store(&wavepart[(iter & 1) * 2048 + bid * 8 + wid], sq,
                               __ATOMIC_RELEASE, __HIP_MEMORY_SCOPE_AGENT);
        grid.sync();

        // every wave redundantly sums all 2048 partials in identical fixed order
        float psum = 0.0f;
        const float* wp = wavepart + (iter & 1) * 2048;
#pragma unroll 4
        for (int k = 0; k < 32; ++k)
            psum += __hip_atomic_load(&wp[lane + 64 * k], __ATOMIC_RELAXED, __HIP_MEMORY_SCOPE_AGENT);
#pragma unroll
        for (int off = 32; off > 0; off >>= 1) psum += __shfl_xor(psum, off);
        const float tot = psum;

        const float err_norm = sqrtf(tot * (1.0f / (float)(BATCH * 64)));
        const bool accept = (err_norm <= 1.0f) && (!done);
        float factor = SAFETY_C * powf(fmaxf(err_norm, 1e-10f), -0.2f);
        factor = fminf(fmaxf(factor, MINFAC_C), MAXFAC_C);

        if (accept) {
#pragma unroll
            for (int i = 0; i < 16; ++i) { y[i] = y5[i]; k1[i] = k7[i]; }
            t = t + hs;
        }
        h = hs * factor;
        done = done || (t >= T_DONE);
        if (done) break;   // uniform: identical err_norm in every block
    }

    // final store
#pragma unroll
    for (int m = 0; m < 4; ++m) {
        f4v v;
        v.x = y[4*m+0]; v.y = y[4*m+1]; v.z = y[4*m+2]; v.w = y[4*m+3];
        *(f4v*)(Y + (row0 + b) * 64 + m*16 + 4*g) = v;
    }
}

extern "C" void kernel_launch(void* const* d_in, const int* in_sizes, int n_in,
                              void* d_out, int out_size, void* d_ws, size_t ws_size,
                              hipStream_t stream) {
    const float* x  = (const float*)d_in[0];
    const float* W1 = (const float*)d_in[1];
    const float* b1 = (const float*)d_in[2];
    const float* W2 = (const float*)d_in[3];
    const float* b2 = (const float*)d_in[4];
    const float* W3 = (const float*)d_in[5];
    const float* b3 = (const float*)d_in[6];
    float* Y  = (float*)d_out;
    float* ws = (float*)d_ws;

    // wavepart [2][2048] f32 + 32 KB frag-linear W2
    const size_t need = (size_t)(2 * 2048) * sizeof(float) + 32768;
    if (ws_size < need) return;

    (void)hipFuncSetAttribute(reinterpret_cast<const void*>(ode_kernel),
                              hipFuncAttributeMaxDynamicSharedMemorySize, LDS_BYTES);

    void* args[] = {(void*)&x, (void*)&W1, (void*)&b1, (void*)&W2, (void*)&b2,
                    (void*)&W3, (void*)&b3, (void*)&Y, (void*)&ws};
    (void)hipLaunchCooperativeKernel(reinterpret_cast<const void*>(ode_kernel),
                                     dim3(NBLOCKS), dim3(NTHREADS),
                                     args, LDS_BYTES, stream);
}

// Round 10
// 285.670 us; speedup vs baseline: 1.6786x; 1.5879x over previous
//
#include <hip/hip_runtime.h>
#include <hip/hip_cooperative_groups.h>

namespace cg = cooperative_groups;

#define BATCH   32768
#define NBLOCKS 256
#define NTHREADS 512
#define NWAVES  8

// LDS byte layout:
//   [0, 16384)        W1^T frags  (8 Mtiles x 2 Ktiles x 1KB)
//   [16384, 49152)    W2^T frags  (8 x 4 x 1KB)
//   [49152, 65536)    W3^T frags  (4 x 4 x 1KB)
//   [65536, 131072)   8 waves x 8KB scratch
//   [131072, 132352)  bias f32: b1[128] b2[128] b3[64]
#define LDS_BYTES 132352

typedef short    bf16x8 __attribute__((ext_vector_type(8)));
typedef float    f32x4  __attribute__((ext_vector_type(4)));
typedef unsigned u32x2  __attribute__((ext_vector_type(2)));
typedef float    f4v    __attribute__((ext_vector_type(4)));

#define A21 ((float)(1.0/5.0))
#define A31 ((float)(3.0/40.0))
#define A32 ((float)(9.0/40.0))
#define A41 ((float)(44.0/45.0))
#define A42 ((float)(-56.0/15.0))
#define A43 ((float)(32.0/9.0))
#define A51 ((float)(19372.0/6561.0))
#define A52 ((float)(-25360.0/2187.0))
#define A53 ((float)(64448.0/6561.0))
#define A54 ((float)(-212.0/729.0))
#define A61 ((float)(9017.0/3168.0))
#define A62 ((float)(-355.0/33.0))
#define A63 ((float)(46732.0/5247.0))
#define A64 ((float)(49.0/176.0))
#define A65 ((float)(-5103.0/18656.0))
#define BB1 ((float)(35.0/384.0))
#define BB3 ((float)(500.0/1113.0))
#define BB4 ((float)(125.0/192.0))
#define BB5 ((float)(-2187.0/6784.0))
#define BB6 ((float)(11.0/84.0))
#define E1 (BB1 - (float)(5179.0/57600.0))
#define E3 (BB3 - (float)(7571.0/16695.0))
#define E4 (BB4 - (float)(393.0/640.0))
#define E5 (BB5 - (float)(-92097.0/339200.0))
#define E6 (BB6 - (float)(187.0/2100.0))
#define E7 (0.0f - (float)(1.0/40.0))

#define RTOL_C 1e-3f
#define ATOL_C 1e-3f
#define SAFETY_C 0.9f
#define MINFAC_C 0.2f
#define MAXFAC_C 10.0f
#define H0_C 0.05f
#define T_DONE ((float)(1.0 - 1e-7))

// bf16 round-to-nearest-even (used in one-time weight staging)
__device__ __forceinline__ unsigned bfr(float x) {
    unsigned u = __builtin_bit_cast(unsigned, x);
    return (u + 0x7fffu + ((u >> 16) & 1u)) >> 16;
}

// --- cheap packing helpers for the hot path ---
// truncation-split: hi = a with mantissa低 bits cut (exact), lo = a - hi (exact)
__device__ __forceinline__ float trunchi(float a) {
    return __builtin_bit_cast(float, __builtin_bit_cast(unsigned, a) & 0xffff0000u);
}
// pack bf16(trunc(a)) in lo16, bf16(trunc(b)) in hi16  (3 VALU ops)
__device__ __forceinline__ unsigned packhi2(float a, float b) {
    return (__builtin_bit_cast(unsigned, a) >> 16) |
           (__builtin_bit_cast(unsigned, b) & 0xffff0000u);
}
// HW packed f32->bf16 RNE convert: dst.lo16 = bf16(a), dst.hi16 = bf16(b)
__device__ __forceinline__ unsigned cvtpk2(float a, float b) {
    unsigned r;
    asm("v_cvt_pk_bf16_f32 %0, %1, %2" : "=v"(r) : "v"(a), "v"(b));
    return r;
}

// f(y) for the wave's 16 batch rows, fully MFMA.
// State layout: lane (b = lane&15, g = lane>>4) owns batch row b, dims m*16+4g+r.
// Computes C^T = W^T . Y^T per layer; weights pre-staged as frag-linear bf16 tiles.
// scr: per-wave 8KB; lifetimes: ybuf[0,4K) -> h1_lo[0,4K)+h1_hi[4K,8K) -> h2[0,4K).
__device__ __forceinline__ void feval16(
    const char* __restrict__ wf, const float* __restrict__ biasf,
    char* scr, const int lane, const int b, const int g, const int swzx,
    const float (&ys)[16], float (&kout)[16])
{
    // ---- stage ys -> ybuf (hi=trunc plane, lo=residual plane, swizzled) ----
#pragma unroll
    for (int m = 0; m < 4; ++m) {
        const float a0 = ys[4*m], a1 = ys[4*m+1], a2 = ys[4*m+2], a3 = ys[4*m+3];
        u32x2 vh, vl;
        vh.x = packhi2(a0, a1); vh.y = packhi2(a2, a3);
        vl.x = cvtpk2(a0 - trunchi(a0), a1 - trunchi(a1));
        vl.y = cvtpk2(a2 - trunchi(a2), a3 - trunchi(a3));
        const int off = (b*128 + (m*16 + 4*g)*2) ^ swzx;
        *(u32x2*)(scr + off)        = vh;
        *(u32x2*)(scr + 2048 + off) = vl;
    }
    __builtin_amdgcn_wave_barrier();
    // ---- L1: B-frags from ybuf ----
    bf16x8 Bh0, Bh1, Bl0, Bl1;
    {
        const int o0 = (b*128 + 16*g) ^ swzx;
        const int o1 = (b*128 + 64 + 16*g) ^ swzx;
        Bh0 = *(const bf16x8*)(scr + o0);
        Bh1 = *(const bf16x8*)(scr + o1);
        Bl0 = *(const bf16x8*)(scr + 2048 + o0);
        Bl1 = *(const bf16x8*)(scr + 2048 + o1);
    }
    __builtin_amdgcn_wave_barrier();
#pragma unroll
    for (int m = 0; m < 8; ++m) {
        const f4v bia = *(const f4v*)(biasf + m*16 + 4*g);
        f32x4 acc = {bia.x, bia.y, bia.z, bia.w};           // bias in C-init
        const bf16x8 A0 = *(const bf16x8*)(wf + (m*2+0)*1024 + lane*16);
        const bf16x8 A1 = *(const bf16x8*)(wf + (m*2+1)*1024 + lane*16);
        acc = __builtin_amdgcn_mfma_f32_16x16x32_bf16(A0, Bh0, acc, 0, 0, 0);
        acc = __builtin_amdgcn_mfma_f32_16x16x32_bf16(A1, Bh1, acc, 0, 0, 0);
        acc = __builtin_amdgcn_mfma_f32_16x16x32_bf16(A0, Bl0, acc, 0, 0, 0);
        acc = __builtin_amdgcn_mfma_f32_16x16x32_bf16(A1, Bl1, acc, 0, 0, 0);
        const float v0 = fmaxf(acc[0], 0.f);
        const float v1 = fmaxf(acc[1], 0.f);
        const float v2 = fmaxf(acc[2], 0.f);
        const float v3 = fmaxf(acc[3], 0.f);
        u32x2 vh, vl;
        vh.x = packhi2(v0, v1); vh.y = packhi2(v2, v3);
        vl.x = cvtpk2(v0 - trunchi(v0), v1 - trunchi(v1));
        vl.y = cvtpk2(v2 - trunchi(v2), v3 - trunchi(v3));
        const int off = (b*256 + (m*16 + 4*g)*2) ^ swzx;
        *(u32x2*)(scr + 4096 + off) = vh;     // h1_hi
        *(u32x2*)(scr + off)        = vl;     // h1_lo (ybuf dead)
    }
    __builtin_amdgcn_wave_barrier();
    // ---- L2 ----
    bf16x8 B2h[4], B2l[4];
#pragma unroll
    for (int kt = 0; kt < 4; ++kt) {
        const int off = (b*256 + 64*kt + 16*g) ^ swzx;
        B2h[kt] = *(const bf16x8*)(scr + 4096 + off);
        B2l[kt] = *(const bf16x8*)(scr + off);
    }
    __builtin_amdgcn_wave_barrier();
#pragma unroll
    for (int m = 0; m < 8; ++m) {
        const f4v bia = *(const f4v*)(biasf + 128 + m*16 + 4*g);
        f32x4 acc = {bia.x, bia.y, bia.z, bia.w};
#pragma unroll
        for (int kt = 0; kt < 4; ++kt) {
            const bf16x8 A = *(const bf16x8*)(wf + 16384 + (m*4+kt)*1024 + lane*16);
            acc = __builtin_amdgcn_mfma_f32_16x16x32_bf16(A, B2h[kt], acc, 0, 0, 0);
            acc = __builtin_amdgcn_mfma_f32_16x16x32_bf16(A, B2l[kt], acc, 0, 0, 0);
        }
        const float v0 = fmaxf(acc[0], 0.f);
        const float v1 = fmaxf(acc[1], 0.f);
        const float v2 = fmaxf(acc[2], 0.f);
        const float v3 = fmaxf(acc[3], 0.f);
        u32x2 vh;
        vh.x = cvtpk2(v0, v1); vh.y = cvtpk2(v2, v3);      // h2 hi-only, RNE
        const int off = (b*256 + (m*16 + 4*g)*2) ^ swzx;
        *(u32x2*)(scr + off) = vh;            // h2_hi (h1_lo dead)
    }
    __builtin_amdgcn_wave_barrier();
    // ---- L3 ----
    bf16x8 B3[4];
#pragma unroll
    for (int kt = 0; kt < 4; ++kt)
        B3[kt] = *(const bf16x8*)(scr + ((b*256 + 64*kt + 16*g) ^ swzx));
    __builtin_amdgcn_wave_barrier();
#pragma unroll
    for (int m = 0; m < 4; ++m) {
        const f4v bia = *(const f4v*)(biasf + 256 + m*16 + 4*g);
        f32x4 acc = {bia.x, bia.y, bia.z, bia.w};
#pragma unroll
        for (int kt = 0; kt < 4; ++kt) {
            const bf16x8 A = *(const bf16x8*)(wf + 49152 + (m*4+kt)*1024 + lane*16);
            acc = __builtin_amdgcn_mfma_f32_16x16x32_bf16(A, B3[kt], acc, 0, 0, 0);
        }
        kout[4*m+0] = acc[0];
        kout[4*m+1] = acc[1];
        kout[4*m+2] = acc[2];
        kout[4*m+3] = acc[3];
    }
}

__global__ __launch_bounds__(NTHREADS)
__attribute__((amdgpu_waves_per_eu(2, 2)))
void ode_kernel(
    const float* __restrict__ x,
    const float* __restrict__ gW1, const float* __restrict__ gb1,
    const float* __restrict__ gW2, const float* __restrict__ gb2,
    const float* __restrict__ gW3, const float* __restrict__ gb3,
    float* __restrict__ Y, float* __restrict__ ws)
{
    extern __shared__ float lds[];
    char*  ldsb  = (char*)lds;
    short* wfrag = (short*)ldsb;
    float* biasf = (float*)(ldsb + 131072);

    const int tid  = threadIdx.x;
    const int lane = tid & 63;
    const int wid  = tid >> 6;
    const int bid  = blockIdx.x;
    const int b    = lane & 15;
    const int g    = lane >> 4;
    const int swzx = (b & 7) << 4;

    // ---- stage weights as frag-linear bf16 tiles (once) ----
    for (int i = tid; i < 8192; i += NTHREADS) {       // W1: 16 tiles (m*2+kt)
        const int t = i >> 9, l = (i >> 3) & 63, j = i & 7;
        const int m = t >> 1, kt = t & 1;
        const int row = kt*32 + (l>>4)*8 + j, col = m*16 + (l&15);
        wfrag[i] = (short)bfr(gW1[row*128 + col]);
    }
    for (int i = tid; i < 16384; i += NTHREADS) {      // W2: 32 tiles (m*4+kt)
        const int t = i >> 9, l = (i >> 3) & 63, j = i & 7;
        const int m = t >> 2, kt = t & 3;
        const int row = kt*32 + (l>>4)*8 + j, col = m*16 + (l&15);
        wfrag[8192 + i] = (short)bfr(gW2[row*128 + col]);
    }
    for (int i = tid; i < 8192; i += NTHREADS) {       // W3: 16 tiles (m*4+kt)
        const int t = i >> 9, l = (i >> 3) & 63, j = i & 7;
        const int m = t >> 2, kt = t & 3;
        const int row = kt*32 + (l>>4)*8 + j, col = m*16 + (l&15);
        wfrag[24576 + i] = (short)bfr(gW3[row*64 + col]);
    }
    for (int i = tid; i < 128; i += NTHREADS) biasf[i]       = gb1[i];
    for (int i = tid; i < 128; i += NTHREADS) biasf[128 + i] = gb2[i];
    for (int i = tid; i < 64;  i += NTHREADS) biasf[256 + i] = gb3[i];
    __syncthreads();

    char* scr = ldsb + 65536 + wid * 8192;
    float* wavepart = ws;                     // [2][2048] ping-pong

    cg::grid_group grid = cg::this_grid();
    const int row0 = bid * 128 + wid * 16;

    // persistent state: lane owns batch row0+b, dims m*16+4g+r  (idx = m*4+r)
    float y[16], k1[16];

    // ---- prepass: y = x; k1 = f(y) ----
    {
        float ysv[16];
#pragma unroll
        for (int m = 0; m < 4; ++m) {
            const f4v v = *(const f4v*)(x + (row0 + b) * 64 + m*16 + 4*g);
            ysv[4*m+0] = v.x; ysv[4*m+1] = v.y; ysv[4*m+2] = v.z; ysv[4*m+3] = v.w;
        }
#pragma unroll
        for (int i = 0; i < 16; ++i) y[i] = ysv[i];
        feval16(ldsb, biasf, scr, lane, b, g, swzx, ysv, k1);
    }

    float t = 0.0f, h = H0_C;
    bool done = false;

#pragma unroll 1
    for (int iter = 0; iter < 64; ++iter) {
        const float hs = fminf(h, 1.0f - t);
        float sq = 0.0f;
        float y5[16], k7[16];

        // ---- straight-line dopri5 stages (precise liveness) ----
        {
            float ysv[16];
            float k2[16], k3[16], k4[16], k5[16], k6[16], errp[16];

#pragma unroll
            for (int i = 0; i < 16; ++i) ysv[i] = y[i] + hs * (A21 * k1[i]);
            feval16(ldsb, biasf, scr, lane, b, g, swzx, ysv, k2);

#pragma unroll
            for (int i = 0; i < 16; ++i) ysv[i] = y[i] + hs * (A31 * k1[i] + A32 * k2[i]);
            feval16(ldsb, biasf, scr, lane, b, g, swzx, ysv, k3);

#pragma unroll
            for (int i = 0; i < 16; ++i) ysv[i] = y[i] + hs * (A41 * k1[i] + A42 * k2[i] + A43 * k3[i]);
            feval16(ldsb, biasf, scr, lane, b, g, swzx, ysv, k4);

#pragma unroll
            for (int i = 0; i < 16; ++i) ysv[i] = y[i] + hs * (A51 * k1[i] + A52 * k2[i] + A53 * k3[i] + A54 * k4[i]);
            feval16(ldsb, biasf, scr, lane, b, g, swzx, ysv, k5);

#pragma unroll
            for (int i = 0; i < 16; ++i) ysv[i] = y[i] + hs * (A61 * k1[i] + A62 * k2[i] + A63 * k3[i] + A64 * k4[i] + A65 * k5[i]);
            feval16(ldsb, biasf, scr, lane, b, g, swzx, ysv, k6);   // k2 dead

#pragma unroll
            for (int i = 0; i < 16; ++i) {
                ysv[i]  = y[i] + hs * (BB1 * k1[i] + BB3 * k3[i] + BB4 * k4[i] + BB5 * k5[i] + BB6 * k6[i]);
                y5[i]   = ysv[i];
                errp[i] = hs * (E1 * k1[i] + E3 * k3[i] + E4 * k4[i] + E5 * k5[i] + E6 * k6[i]);
            }                                                        // k3..k6 dead
            feval16(ldsb, biasf, scr, lane, b, g, swzx, ysv, k7);

#pragma unroll
            for (int i = 0; i < 16; ++i) {
                const float er = errp[i] + hs * (E7 * k7[i]);
                const float sc = ATOL_C + RTOL_C * fmaxf(fabsf(y[i]), fabsf(y5[i]));
                const float q = er / sc;
                sq += q * q;
            }
        }

        // wave butterfly reduce (bitwise identical on all lanes)
#pragma unroll
        for (int off = 32; off > 0; off >>= 1) sq += __shfl_xor(sq, off);
        if (lane == 0)
            __hip_atomic_store(&wavepart[(iter & 1) * 2048 + bid * 8 + wid], sq,
                               __ATOMIC_RELEASE, __HIP_MEMORY_SCOPE_AGENT);
        grid.sync();

        // every wave redundantly sums all 2048 partials in identical fixed order
        float psum = 0.0f;
        const float* wp = wavepart + (iter & 1) * 2048;
#pragma unroll 4
        for (int k = 0; k < 32; ++k)
            psum += __hip_atomic_load(&wp[lane + 64 * k], __ATOMIC_RELAXED, __HIP_MEMORY_SCOPE_AGENT);
#pragma unroll
        for (int off = 32; off > 0; off >>= 1) psum += __shfl_xor(psum, off);
        const float tot = psum;

        const float err_norm = sqrtf(tot * (1.0f / (float)(BATCH * 64)));
        const bool accept = (err_norm <= 1.0f) && (!done);
        float factor = SAFETY_C * powf(fmaxf(err_norm, 1e-10f), -0.2f);
        factor = fminf(fmaxf(factor, MINFAC_C), MAXFAC_C);

        if (accept) {
#pragma unroll
            for (int i = 0; i < 16; ++i) { y[i] = y5[i]; k1[i] = k7[i]; }
            t = t + hs;
        }
        h = hs * factor;
        done = done || (t >= T_DONE);
        if (done) break;   // uniform: identical err_norm in every block
    }

    // final store
#pragma unroll
    for (int m = 0; m < 4; ++m) {
        f4v v;
        v.x = y[4*m+0]; v.y = y[4*m+1]; v.z = y[4*m+2]; v.w = y[4*m+3];
        *(f4v*)(Y + (row0 + b) * 64 + m*16 + 4*g) = v;
    }
}

extern "C" void kernel_launch(void* const* d_in, const int* in_sizes, int n_in,
                              void* d_out, int out_size, void* d_ws, size_t ws_size,
                              hipStream_t stream) {
    const float* x  = (const float*)d_in[0];
    const float* W1 = (const float*)d_in[1];
    const float* b1 = (const float*)d_in[2];
    const float* W2 = (const float*)d_in[3];
    const float* b2 = (const float*)d_in[4];
    const float* W3 = (const float*)d_in[5];
    const float* b3 = (const float*)d_in[6];
    float* Y  = (float*)d_out;
    float* ws = (float*)d_ws;

    const size_t need = (size_t)(2 * 2048) * sizeof(float);
    if (ws_size < need) return;

    (void)hipFuncSetAttribute(reinterpret_cast<const void*>(ode_kernel),
                              hipFuncAttributeMaxDynamicSharedMemorySize, LDS_BYTES);

    void* args[] = {(void*)&x, (void*)&W1, (void*)&b1, (void*)&W2, (void*)&b2,
                    (void*)&W3, (void*)&b3, (void*)&Y, (void*)&ws};
    (void)hipLaunchCooperativeKernel(reinterpret_cast<const void*>(ode_kernel),
                                     dim3(NBLOCKS), dim3(NTHREADS),
                                     args, LDS_BYTES, stream);
}

// Round 11
// 269.079 us; speedup vs baseline: 1.7821x; 1.0617x over previous
//
#include <hip/hip_runtime.h>
#include <hip/hip_cooperative_groups.h>

namespace cg = cooperative_groups;

#define BATCH   32768
#define NBLOCKS 256
#define NTHREADS 512
#define NWAVES  8

// LDS byte layout:
//   [0, 16384)        W1^T frags  (8 Mtiles x 2 Ktiles x 1KB)
//   [16384, 49152)    W2^T frags  (8 x 4 x 1KB)
//   [49152, 65536)    W3^T frags  (4 x 4 x 1KB)
//   [65536, 131072)   8 waves x 8KB scratch
//   [131072, 132352)  bias f32: b1[128] b2[128] b3[64]
#define LDS_BYTES 132352

typedef short    bf16x8 __attribute__((ext_vector_type(8)));
typedef float    f32x4  __attribute__((ext_vector_type(4)));
typedef unsigned u32x2  __attribute__((ext_vector_type(2)));
typedef float    f4v    __attribute__((ext_vector_type(4)));

#define A21 ((float)(1.0/5.0))
#define A31 ((float)(3.0/40.0))
#define A32 ((float)(9.0/40.0))
#define A41 ((float)(44.0/45.0))
#define A42 ((float)(-56.0/15.0))
#define A43 ((float)(32.0/9.0))
#define A51 ((float)(19372.0/6561.0))
#define A52 ((float)(-25360.0/2187.0))
#define A53 ((float)(64448.0/6561.0))
#define A54 ((float)(-212.0/729.0))
#define A61 ((float)(9017.0/3168.0))
#define A62 ((float)(-355.0/33.0))
#define A63 ((float)(46732.0/5247.0))
#define A64 ((float)(49.0/176.0))
#define A65 ((float)(-5103.0/18656.0))
#define BB1 ((float)(35.0/384.0))
#define BB3 ((float)(500.0/1113.0))
#define BB4 ((float)(125.0/192.0))
#define BB5 ((float)(-2187.0/6784.0))
#define BB6 ((float)(11.0/84.0))
#define E1 (BB1 - (float)(5179.0/57600.0))
#define E3 (BB3 - (float)(7571.0/16695.0))
#define E4 (BB4 - (float)(393.0/640.0))
#define E5 (BB5 - (float)(-92097.0/339200.0))
#define E6 (BB6 - (float)(187.0/2100.0))
#define E7 (0.0f - (float)(1.0/40.0))

#define RTOL_C 1e-3f
#define ATOL_C 1e-3f
#define SAFETY_C 0.9f
#define MINFAC_C 0.2f
#define MAXFAC_C 10.0f
#define H0_C 0.05f
#define T_DONE ((float)(1.0 - 1e-7))

// bf16 round-to-nearest-even (used in one-time weight staging)
__device__ __forceinline__ unsigned bfr(float x) {
    unsigned u = __builtin_bit_cast(unsigned, x);
    return (u + 0x7fffu + ((u >> 16) & 1u)) >> 16;
}

// --- cheap packing helpers for the hot path ---
// truncation-split: hi = a with low mantissa bits cut (exact), lo = a - hi (exact)
__device__ __forceinline__ float trunchi(float a) {
    return __builtin_bit_cast(float, __builtin_bit_cast(unsigned, a) & 0xffff0000u);
}
// pack bf16(trunc(a)) in lo16, bf16(trunc(b)) in hi16  (3 VALU ops)
__device__ __forceinline__ unsigned packhi2(float a, float b) {
    return (__builtin_bit_cast(unsigned, a) >> 16) |
           (__builtin_bit_cast(unsigned, b) & 0xffff0000u);
}
// HW packed f32->bf16 RNE convert: dst.lo16 = bf16(a), dst.hi16 = bf16(b)
__device__ __forceinline__ unsigned cvtpk2(float a, float b) {
    unsigned r;
    asm("v_cvt_pk_bf16_f32 %0, %1, %2" : "=v"(r) : "v"(a), "v"(b));
    return r;
}

// f(y) for the wave's 16 batch rows, fully MFMA.
// State layout: lane (b = lane&15, g = lane>>4) owns batch row b, dims m*16+4g+r.
// y is staged hi+lo (integration-state precision); h1 and h2 are single RNE
// bf16 planes (activation precision ~2e-3 rel, within dopri5 error control).
// scr: per-wave 8KB; lifetimes: ybuf[0,4K) -> h1_hi[4K,8K) -> h2[0,4K).
__device__ __forceinline__ void feval16(
    const char* __restrict__ wf, const float* __restrict__ biasf,
    char* scr, const int lane, const int b, const int g, const int swzx,
    const float (&ys)[16], float (&kout)[16])
{
    // ---- stage ys -> ybuf (hi=trunc plane, lo=residual plane, swizzled) ----
#pragma unroll
    for (int m = 0; m < 4; ++m) {
        const float a0 = ys[4*m], a1 = ys[4*m+1], a2 = ys[4*m+2], a3 = ys[4*m+3];
        u32x2 vh, vl;
        vh.x = packhi2(a0, a1); vh.y = packhi2(a2, a3);
        vl.x = cvtpk2(a0 - trunchi(a0), a1 - trunchi(a1));
        vl.y = cvtpk2(a2 - trunchi(a2), a3 - trunchi(a3));
        const int off = (b*128 + (m*16 + 4*g)*2) ^ swzx;
        *(u32x2*)(scr + off)        = vh;
        *(u32x2*)(scr + 2048 + off) = vl;
    }
    __builtin_amdgcn_wave_barrier();
    // ---- L1: B-frags from ybuf ----
    bf16x8 Bh0, Bh1, Bl0, Bl1;
    {
        const int o0 = (b*128 + 16*g) ^ swzx;
        const int o1 = (b*128 + 64 + 16*g) ^ swzx;
        Bh0 = *(const bf16x8*)(scr + o0);
        Bh1 = *(const bf16x8*)(scr + o1);
        Bl0 = *(const bf16x8*)(scr + 2048 + o0);
        Bl1 = *(const bf16x8*)(scr + 2048 + o1);
    }
    __builtin_amdgcn_wave_barrier();
#pragma unroll
    for (int m = 0; m < 8; ++m) {
        const f4v bia = *(const f4v*)(biasf + m*16 + 4*g);
        f32x4 acc = {bia.x, bia.y, bia.z, bia.w};           // bias in C-init
        const bf16x8 A0 = *(const bf16x8*)(wf + (m*2+0)*1024 + lane*16);
        const bf16x8 A1 = *(const bf16x8*)(wf + (m*2+1)*1024 + lane*16);
        acc = __builtin_amdgcn_mfma_f32_16x16x32_bf16(A0, Bh0, acc, 0, 0, 0);
        acc = __builtin_amdgcn_mfma_f32_16x16x32_bf16(A1, Bh1, acc, 0, 0, 0);
        acc = __builtin_amdgcn_mfma_f32_16x16x32_bf16(A0, Bl0, acc, 0, 0, 0);
        acc = __builtin_amdgcn_mfma_f32_16x16x32_bf16(A1, Bl1, acc, 0, 0, 0);
        const float v0 = fmaxf(acc[0], 0.f);
        const float v1 = fmaxf(acc[1], 0.f);
        const float v2 = fmaxf(acc[2], 0.f);
        const float v3 = fmaxf(acc[3], 0.f);
        u32x2 vh;
        vh.x = cvtpk2(v0, v1); vh.y = cvtpk2(v2, v3);       // h1 single RNE plane
        const int off = (b*256 + (m*16 + 4*g)*2) ^ swzx;
        *(u32x2*)(scr + 4096 + off) = vh;     // h1_hi
    }
    __builtin_amdgcn_wave_barrier();
    // ---- L2 (h1 single-plane) ----
    bf16x8 B2h[4];
#pragma unroll
    for (int kt = 0; kt < 4; ++kt) {
        const int off = (b*256 + 64*kt + 16*g) ^ swzx;
        B2h[kt] = *(const bf16x8*)(scr + 4096 + off);
    }
    __builtin_amdgcn_wave_barrier();
#pragma unroll
    for (int m = 0; m < 8; ++m) {
        const f4v bia = *(const f4v*)(biasf + 128 + m*16 + 4*g);
        f32x4 acc = {bia.x, bia.y, bia.z, bia.w};
#pragma unroll
        for (int kt = 0; kt < 4; ++kt) {
            const bf16x8 A = *(const bf16x8*)(wf + 16384 + (m*4+kt)*1024 + lane*16);
            acc = __builtin_amdgcn_mfma_f32_16x16x32_bf16(A, B2h[kt], acc, 0, 0, 0);
        }
        const float v0 = fmaxf(acc[0], 0.f);
        const float v1 = fmaxf(acc[1], 0.f);
        const float v2 = fmaxf(acc[2], 0.f);
        const float v3 = fmaxf(acc[3], 0.f);
        u32x2 vh;
        vh.x = cvtpk2(v0, v1); vh.y = cvtpk2(v2, v3);      // h2 RNE plane
        const int off = (b*256 + (m*16 + 4*g)*2) ^ swzx;
        *(u32x2*)(scr + off) = vh;            // h2 (ybuf dead)
    }
    __builtin_amdgcn_wave_barrier();
    // ---- L3 ----
    bf16x8 B3[4];
#pragma unroll
    for (int kt = 0; kt < 4; ++kt)
        B3[kt] = *(const bf16x8*)(scr + ((b*256 + 64*kt + 16*g) ^ swzx));
    __builtin_amdgcn_wave_barrier();
#pragma unroll
    for (int m = 0; m < 4; ++m) {
        const f4v bia = *(const f4v*)(biasf + 256 + m*16 + 4*g);
        f32x4 acc = {bia.x, bia.y, bia.z, bia.w};
#pragma unroll
        for (int kt = 0; kt < 4; ++kt) {
            const bf16x8 A = *(const bf16x8*)(wf + 49152 + (m*4+kt)*1024 + lane*16);
            acc = __builtin_amdgcn_mfma_f32_16x16x32_bf16(A, B3[kt], acc, 0, 0, 0);
        }
        kout[4*m+0] = acc[0];
        kout[4*m+1] = acc[1];
        kout[4*m+2] = acc[2];
        kout[4*m+3] = acc[3];
    }
}

__global__ __launch_bounds__(NTHREADS)
__attribute__((amdgpu_waves_per_eu(2, 2)))
void ode_kernel(
    const float* __restrict__ x,
    const float* __restrict__ gW1, const float* __restrict__ gb1,
    const float* __restrict__ gW2, const float* __restrict__ gb2,
    const float* __restrict__ gW3, const float* __restrict__ gb3,
    float* __restrict__ Y, float* __restrict__ ws)
{
    extern __shared__ float lds[];
    char*  ldsb  = (char*)lds;
    short* wfrag = (short*)ldsb;
    float* biasf = (float*)(ldsb + 131072);

    const int tid  = threadIdx.x;
    const int lane = tid & 63;
    const int wid  = tid >> 6;
    const int bid  = blockIdx.x;
    const int b    = lane & 15;
    const int g    = lane >> 4;
    const int swzx = (b & 7) << 4;

    // ---- stage weights as frag-linear bf16 tiles (once) ----
    for (int i = tid; i < 8192; i += NTHREADS) {       // W1: 16 tiles (m*2+kt)
        const int t = i >> 9, l = (i >> 3) & 63, j = i & 7;
        const int m = t >> 1, kt = t & 1;
        const int row = kt*32 + (l>>4)*8 + j, col = m*16 + (l&15);
        wfrag[i] = (short)bfr(gW1[row*128 + col]);
    }
    for (int i = tid; i < 16384; i += NTHREADS) {      // W2: 32 tiles (m*4+kt)
        const int t = i >> 9, l = (i >> 3) & 63, j = i & 7;
        const int m = t >> 2, kt = t & 3;
        const int row = kt*32 + (l>>4)*8 + j, col = m*16 + (l&15);
        wfrag[8192 + i] = (short)bfr(gW2[row*128 + col]);
    }
    for (int i = tid; i < 8192; i += NTHREADS) {       // W3: 16 tiles (m*4+kt)
        const int t = i >> 9, l = (i >> 3) & 63, j = i & 7;
        const int m = t >> 2, kt = t & 3;
        const int row = kt*32 + (l>>4)*8 + j, col = m*16 + (l&15);
        wfrag[24576 + i] = (short)bfr(gW3[row*64 + col]);
    }
    for (int i = tid; i < 128; i += NTHREADS) biasf[i]       = gb1[i];
    for (int i = tid; i < 128; i += NTHREADS) biasf[128 + i] = gb2[i];
    for (int i = tid; i < 64;  i += NTHREADS) biasf[256 + i] = gb3[i];
    __syncthreads();

    char* scr = ldsb + 65536 + wid * 8192;
    float* wavepart = ws;                     // [2][2048] ping-pong

    cg::grid_group grid = cg::this_grid();
    const int row0 = bid * 128 + wid * 16;

    // persistent state: lane owns batch row0+b, dims m*16+4g+r  (idx = m*4+r)
    float y[16], k1[16];

    // ---- prepass: y = x; k1 = f(y) ----
    {
        float ysv[16];
#pragma unroll
        for (int m = 0; m < 4; ++m) {
            const f4v v = *(const f4v*)(x + (row0 + b) * 64 + m*16 + 4*g);
            ysv[4*m+0] = v.x; ysv[4*m+1] = v.y; ysv[4*m+2] = v.z; ysv[4*m+3] = v.w;
        }
#pragma unroll
        for (int i = 0; i < 16; ++i) y[i] = ysv[i];
        feval16(ldsb, biasf, scr, lane, b, g, swzx, ysv, k1);
    }

    float t = 0.0f, h = H0_C;
    bool done = false;

#pragma unroll 1
    for (int iter = 0; iter < 64; ++iter) {
        const float hs = fminf(h, 1.0f - t);
        float sq = 0.0f;
        float y5[16], k7[16];

        // ---- straight-line dopri5 stages (precise liveness) ----
        {
            float ysv[16];
            float k2[16], k3[16], k4[16], k5[16], k6[16], errp[16];

#pragma unroll
            for (int i = 0; i < 16; ++i) ysv[i] = y[i] + hs * (A21 * k1[i]);
            feval16(ldsb, biasf, scr, lane, b, g, swzx, ysv, k2);

#pragma unroll
            for (int i = 0; i < 16; ++i) ysv[i] = y[i] + hs * (A31 * k1[i] + A32 * k2[i]);
            feval16(ldsb, biasf, scr, lane, b, g, swzx, ysv, k3);

#pragma unroll
            for (int i = 0; i < 16; ++i) ysv[i] = y[i] + hs * (A41 * k1[i] + A42 * k2[i] + A43 * k3[i]);
            feval16(ldsb, biasf, scr, lane, b, g, swzx, ysv, k4);

#pragma unroll
            for (int i = 0; i < 16; ++i) ysv[i] = y[i] + hs * (A51 * k1[i] + A52 * k2[i] + A53 * k3[i] + A54 * k4[i]);
            feval16(ldsb, biasf, scr, lane, b, g, swzx, ysv, k5);

#pragma unroll
            for (int i = 0; i < 16; ++i) ysv[i] = y[i] + hs * (A61 * k1[i] + A62 * k2[i] + A63 * k3[i] + A64 * k4[i] + A65 * k5[i]);
            feval16(ldsb, biasf, scr, lane, b, g, swzx, ysv, k6);   // k2 dead

#pragma unroll
            for (int i = 0; i < 16; ++i) {
                ysv[i]  = y[i] + hs * (BB1 * k1[i] + BB3 * k3[i] + BB4 * k4[i] + BB5 * k5[i] + BB6 * k6[i]);
                y5[i]   = ysv[i];
                errp[i] = hs * (E1 * k1[i] + E3 * k3[i] + E4 * k4[i] + E5 * k5[i] + E6 * k6[i]);
            }                                                        // k3..k6 dead
            feval16(ldsb, biasf, scr, lane, b, g, swzx, ysv, k7);

#pragma unroll
            for (int i = 0; i < 16; ++i) {
                const float er = errp[i] + hs * (E7 * k7[i]);
                const float sc = ATOL_C + RTOL_C * fmaxf(fabsf(y[i]), fabsf(y5[i]));
                const float q = er / sc;
                sq += q * q;
            }
        }

        // wave butterfly reduce (bitwise identical on all lanes)
#pragma unroll
        for (int off = 32; off > 0; off >>= 1) sq += __shfl_xor(sq, off);
        if (lane == 0)
            __hip_atomic_store(&wavepart[(iter & 1) * 2048 + bid * 8 + wid], sq,
                               __ATOMIC_RELEASE, __HIP_MEMORY_SCOPE_AGENT);
        grid.sync();

        // every wave redundantly sums all 2048 partials in identical fixed order
        float psum = 0.0f;
        const float* wp = wavepart + (iter & 1) * 2048;
#pragma unroll 4
        for (int k = 0; k < 32; ++k)
            psum += __hip_atomic_load(&wp[lane + 64 * k], __ATOMIC_RELAXED, __HIP_MEMORY_SCOPE_AGENT);
#pragma unroll
        for (int off = 32; off > 0; off >>= 1) psum += __shfl_xor(psum, off);
        const float tot = psum;

        const float err_norm = sqrtf(tot * (1.0f / (float)(BATCH * 64)));
        const bool accept = (err_norm <= 1.0f) && (!done);
        float factor = SAFETY_C * powf(fmaxf(err_norm, 1e-10f), -0.2f);
        factor = fminf(fmaxf(factor, MINFAC_C), MAXFAC_C);

        if (accept) {
#pragma unroll
            for (int i = 0; i < 16; ++i) { y[i] = y5[i]; k1[i] = k7[i]; }
            t = t + hs;
        }
        h = hs * factor;
        done = done || (t >= T_DONE);
        if (done) break;   // uniform: identical err_norm in every block
    }

    // final store
#pragma unroll
    for (int m = 0; m < 4; ++m) {
        f4v v;
        v.x = y[4*m+0]; v.y = y[4*m+1]; v.z = y[4*m+2]; v.w = y[4*m+3];
        *(f4v*)(Y + (row0 + b) * 64 + m*16 + 4*g) = v;
    }
}

extern "C" void kernel_launch(void* const* d_in, const int* in_sizes, int n_in,
                              void* d_out, int out_size, void* d_ws, size_t ws_size,
                              hipStream_t stream) {
    const float* x  = (const float*)d_in[0];
    const float* W1 = (const float*)d_in[1];
    const float* b1 = (const float*)d_in[2];
    const float* W2 = (const float*)d_in[3];
    const float* b2 = (const float*)d_in[4];
    const float* W3 = (const float*)d_in[5];
    const float* b3 = (const float*)d_in[6];
    float* Y  = (float*)d_out;
    float* ws = (float*)d_ws;

    const size_t need = (size_t)(2 * 2048) * sizeof(float);
    if (ws_size < need) return;

    (void)hipFuncSetAttribute(reinterpret_cast<const void*>(ode_kernel),
                              hipFuncAttributeMaxDynamicSharedMemorySize, LDS_BYTES);

    void* args[] = {(void*)&x, (void*)&W1, (void*)&b1, (void*)&W2, (void*)&b2,
                    (void*)&W3, (void*)&b3, (void*)&Y, (void*)&ws};
    (void)hipLaunchCooperativeKernel(reinterpret_cast<const void*>(ode_kernel),
                                     dim3(NBLOCKS), dim3(NTHREADS),
                                     args, LDS_BYTES, stream);
}